// Round 2
// baseline (123.325 us; speedup 1.0000x reference)
//
#include <hip/hip_runtime.h>

// KMeans soft-assignment via bf16 hi/lo split MFMA (3 passes), fused softmax.
// logits = (2*x.c - ||c||^2)/T, T=0.1; ||x||^2 cancels in softmax.
// R12: NO LDS STAGING, NO K-LOOP BARRIERS. R10/R11 post-mortem: both
// barrier-lockstep staging structures stall at vmcnt(0)+s_barrier every
// K-iter (MfmaUtil ~20%); co-resident blocks don't fill it (R11 regressed).
// B is only 512 KB -> L2/L1-resident; LDS round-trip buys nothing. prep_c
// now emits B in FRAGMENT-MAJOR layout (per 16-col tile: 64 lanes x 16B
// contiguous), main loop loads each MFMA B-operand as one coalesced 1KB
// global_load_dwordx4, 2-group register pipeline, waves fully independent.
// LDS used only by the transpose epilogue (66 KB lbuf + 2 KB red).
// x: [32768,256] f32, c: [512,256] f32, out: [32768,512] f32
#define NROWS 32768
#define KC 512
#define DDIM 256
#define BM 128
#define BK 32
#define KCH (DDIM / BK)        // 8 k-chunks

typedef __attribute__((ext_vector_type(8))) short bf16x8;
typedef __attribute__((ext_vector_type(4))) float f32x4;

union U8 { unsigned short u[8]; bf16x8 v; };

__device__ __forceinline__ unsigned short f2bf(float f) {   // RNE f32->bf16
    union { float f; unsigned int u; } a; a.f = f;
    unsigned int r = a.u + 0x7fffu + ((a.u >> 16) & 1u);
    return (unsigned short)(r >> 16);
}
__device__ __forceinline__ float bf2f(unsigned short h) {
    union { unsigned int u; float f; } a; a.u = ((unsigned int)h) << 16;
    return a.f;
}

// ---- prep: c -> fragment-major bf16 hi/lo + csq10 ----
// Fragment (ks, t) = B-operand for k-chunk ks, 16-col tile t, stored as
// 64 lanes x 8 ushorts contiguous (1 KB): lane l = octet for col (t*16+(l&15)),
// k = ks*32 + (l>>4)*8 .. +7.  Main-loop load: base + lane*16B, coalesced.
__global__ __launch_bounds__(64) void prep_c(const float* __restrict__ c,
                                             unsigned short* __restrict__ bhi,
                                             unsigned short* __restrict__ blo,
                                             float* __restrict__ csq10) {
    const int n = blockIdx.x, lane = threadIdx.x;
    const int d0 = lane * 4;
    float4 v = ((const float4*)(c + (size_t)n * DDIM))[lane];
    float vv[4] = {v.x, v.y, v.z, v.w};
    unsigned short hh[4], ll[4];
    float ssq = 0.f;
    #pragma unroll
    for (int i = 0; i < 4; ++i) {
        ssq += vv[i] * vv[i];
        hh[i] = f2bf(vv[i]);
        ll[i] = f2bf(vv[i] - bf2f(hh[i]));
    }
    #pragma unroll
    for (int off = 32; off; off >>= 1) ssq += __shfl_xor(ssq, off);
    if (lane == 0) csq10[n] = 10.f * ssq;
    const int ks = d0 >> 5;            // k-chunk
    const int q  = (d0 >> 3) & 3;      // k-octet within chunk
    const int t  = n >> 4, cc = n & 15;
    const size_t dst = ((size_t)(ks * 32 + t) * 64 + (q * 16 + cc)) * 8 + (d0 & 7);
    *(ushort4*)(bhi + dst) = make_ushort4(hh[0], hh[1], hh[2], hh[3]);
    *(ushort4*)(blo + dst) = make_ushort4(ll[0], ll[1], ll[2], ll[3]);
}

// ---- main: 256 blocks x 512 threads (8 waves = 4 M-groups x 2 N-halves) ----
__global__ __launch_bounds__(512, 2) void kmeans_mfma(
    const float* __restrict__ x, const unsigned short* __restrict__ bhi,
    const unsigned short* __restrict__ blo, const float* __restrict__ csq10,
    float* __restrict__ out) {
    __shared__ __align__(16) float lbuf[32 * 516];   // 66 KB (epilogue only)
    __shared__ float red[2][2][BM];                  // 2 KB

    const int tid  = threadIdx.x;
    const int w    = tid >> 6, lane = tid & 63;
    const int wm   = w >> 1, wn = w & 1;
    const int cc   = lane & 15, q = lane >> 4;
    const int row0 = blockIdx.x * BM;

    f32x4 acc[2][16];
    #pragma unroll
    for (int mt = 0; mt < 2; ++mt)
        #pragma unroll
        for (int t = 0; t < 16; ++t) acc[mt][t] = (f32x4){0.f, 0.f, 0.f, 0.f};

    // A: lane owns rows (row0 + wm*32 + mt*16 + cc), k-octet q*8 per chunk
    const float* xA0 = x + (size_t)(row0 + wm * 32 + cc) * DDIM + q * 8;
    const float* xA1 = xA0 + (size_t)16 * DDIM;

    // ---- prologue: load A(0) raw ----
    float4 c00 = *(const float4*)xA0;
    float4 c01 = *(const float4*)(xA0 + 4);
    float4 c10 = *(const float4*)xA1;
    float4 c11 = *(const float4*)(xA1 + 4);

    for (int ks = 0; ks < KCH; ++ks) {
        float4 n00, n01, n10, n11;
        if (ks < KCH - 1) {
            const int kn = (ks + 1) * BK;
            n00 = *(const float4*)(xA0 + kn);
            n01 = *(const float4*)(xA0 + kn + 4);
            n10 = *(const float4*)(xA1 + kn);
            n11 = *(const float4*)(xA1 + kn + 4);
        }
        // convert current A to hi/lo fragments
        bf16x8 ah[2], al[2];
        {
            float v0[8] = {c00.x, c00.y, c00.z, c00.w, c01.x, c01.y, c01.z, c01.w};
            float v1[8] = {c10.x, c10.y, c10.z, c10.w, c11.x, c11.y, c11.z, c11.w};
            U8 H0, L0, H1, L1;
            #pragma unroll
            for (int e = 0; e < 8; ++e) {
                H0.u[e] = f2bf(v0[e]); L0.u[e] = f2bf(v0[e] - bf2f(H0.u[e]));
                H1.u[e] = f2bf(v1[e]); L1.u[e] = f2bf(v1[e] - bf2f(H1.u[e]));
            }
            ah[0] = H0.v; al[0] = L0.v; ah[1] = H1.v; al[1] = L1.v;
        }
        // B direct from global, 2-group register pipeline over 16 col-tiles.
        // bhp/blp: this wave's fragment base for chunk ks; +t*512 per tile,
        // +lane*8 ushorts (=16B) -> one coalesced 1KB load per fragment.
        const unsigned short* bhp = bhi + ((size_t)(ks * 32 + wn * 16) << 9) + lane * 8;
        const unsigned short* blp = blo + ((size_t)(ks * 32 + wn * 16) << 9) + lane * 8;
        bf16x8 pb[2][2][2];   // [parity][tt][hi/lo] -- static after unroll
        pb[0][0][0] = *(const bf16x8*)(bhp);
        pb[0][0][1] = *(const bf16x8*)(blp);
        pb[0][1][0] = *(const bf16x8*)(bhp + 512);
        pb[0][1][1] = *(const bf16x8*)(blp + 512);
        #pragma unroll
        for (int tg = 0; tg < 8; ++tg) {
            const int par = tg & 1, nxt = par ^ 1;
            if (tg < 7) {
                pb[nxt][0][0] = *(const bf16x8*)(bhp + (2 * tg + 2) * 512);
                pb[nxt][0][1] = *(const bf16x8*)(blp + (2 * tg + 2) * 512);
                pb[nxt][1][0] = *(const bf16x8*)(bhp + (2 * tg + 3) * 512);
                pb[nxt][1][1] = *(const bf16x8*)(blp + (2 * tg + 3) * 512);
            }
            #pragma unroll
            for (int tt = 0; tt < 2; ++tt) {
                const int t = 2 * tg + tt;
                bf16x8 bh = pb[par][tt][0];
                bf16x8 bl = pb[par][tt][1];
                acc[0][t] = __builtin_amdgcn_mfma_f32_16x16x32_bf16(ah[0], bh, acc[0][t], 0, 0, 0);
                acc[1][t] = __builtin_amdgcn_mfma_f32_16x16x32_bf16(ah[1], bh, acc[1][t], 0, 0, 0);
                acc[0][t] = __builtin_amdgcn_mfma_f32_16x16x32_bf16(ah[0], bl, acc[0][t], 0, 0, 0);
                acc[1][t] = __builtin_amdgcn_mfma_f32_16x16x32_bf16(ah[1], bl, acc[1][t], 0, 0, 0);
                acc[0][t] = __builtin_amdgcn_mfma_f32_16x16x32_bf16(al[0], bh, acc[0][t], 0, 0, 0);
                acc[1][t] = __builtin_amdgcn_mfma_f32_16x16x32_bf16(al[1], bh, acc[1][t], 0, 0, 0);
            }
        }
        c00 = n00; c01 = n01; c10 = n10; c11 = n11;
    }

    // ---- softmax stats: reduce over t, then cc-lanes, then wn pair via LDS ----
    float csqv[16];
    #pragma unroll
    for (int t = 0; t < 16; ++t) csqv[t] = csq10[wn * 256 + t * 16 + cc];
    const int rb = wm * 32 + q * 4;   // + mt*16 + g
    float M[2][4], I[2][4];
    #pragma unroll
    for (int mt = 0; mt < 2; ++mt)
        #pragma unroll
        for (int g = 0; g < 4; ++g) {
            float pm = -1e30f;
            #pragma unroll
            for (int t = 0; t < 16; ++t) pm = fmaxf(pm, 20.f * acc[mt][t][g] - csqv[t]);
            #pragma unroll
            for (int off = 1; off < 16; off <<= 1) pm = fmaxf(pm, __shfl_xor(pm, off));
            if (cc == 0) red[0][wn][rb + mt * 16 + g] = pm;
            M[mt][g] = pm;
        }
    __syncthreads();
    #pragma unroll
    for (int mt = 0; mt < 2; ++mt)
        #pragma unroll
        for (int g = 0; g < 4; ++g) {
            M[mt][g] = fmaxf(M[mt][g], red[0][1 - wn][rb + mt * 16 + g]);
            float ps = 0.f;
            #pragma unroll
            for (int t = 0; t < 16; ++t) ps += __expf(20.f * acc[mt][t][g] - csqv[t] - M[mt][g]);
            #pragma unroll
            for (int off = 1; off < 16; off <<= 1) ps += __shfl_xor(ps, off);
            if (cc == 0) red[1][wn][rb + mt * 16 + g] = ps;
        }
    __syncthreads();
    #pragma unroll
    for (int mt = 0; mt < 2; ++mt)
        #pragma unroll
        for (int g = 0; g < 4; ++g)
            I[mt][g] = 1.f / (red[1][0][rb + mt * 16 + g] + red[1][1][rb + mt * 16 + g]);

    // ---- transpose epilogue: 4 passes of 32 rows through lbuf, dense stores ----
    #pragma unroll
    for (int p = 0; p < 4; ++p) {
        if (wm == p) {
            #pragma unroll
            for (int mt = 0; mt < 2; ++mt)
                #pragma unroll
                for (int g = 0; g < 4; ++g) {
                    const int   lr = mt * 16 + q * 4 + g;
                    const float mg = M[mt][g], ig = I[mt][g];
                    #pragma unroll
                    for (int t = 0; t < 16; ++t)
                        lbuf[lr * 516 + wn * 256 + t * 16 + cc] =
                            __expf(20.f * acc[mt][t][g] - csqv[t] - mg) * ig;
                }
        }
        __syncthreads();
        #pragma unroll
        for (int j = 0; j < 8; ++j) {
            const int f    = j * 512 + tid;     // 0..4095 float4 slots
            const int lrow = f >> 7;            // 0..31
            const int c4   = f & 127;
            float4    v    = *(const float4*)&lbuf[lrow * 516 + c4 * 4];
            *(float4*)(out + (size_t)(row0 + p * 32 + lrow) * KC + c4 * 4) = v;
        }
        __syncthreads();
    }
}

extern "C" void kernel_launch(void* const* d_in, const int* in_sizes, int n_in,
                              void* d_out, int out_size, void* d_ws, size_t ws_size,
                              hipStream_t stream) {
    const float* x   = (const float*)d_in[0];
    const float* c   = (const float*)d_in[1];
    float*       out = (float*)d_out;

    unsigned short* bhi   = (unsigned short*)d_ws;                    // 256 KB
    unsigned short* blo   = bhi + (size_t)KCH * KC * BK;              // 256 KB
    float*          csq10 = (float*)(blo + (size_t)KCH * KC * BK);    // 2 KB

    prep_c<<<KC, 64, 0, stream>>>(c, bhi, blo, csq10);
    kmeans_mfma<<<NROWS / BM, 512, 0, stream>>>(x, bhi, blo, csq10, out);
}